// Round 1
// baseline (157.262 us; speedup 1.0000x reference)
//
#include <hip/hip_runtime.h>

#define H 1024
#define W 1024
#define F 32
#define K 25
#define TILE_W 256
#define HALO 2
#define LROW (TILE_W + 2*HALO)  // 260

// Transpose weights skv[f][k] -> wt[k][f] so the main kernel's f-inner reads
// are contiguous uniform addresses (s_load_dwordx16 friendly).
__global__ __launch_bounds__(256) void wt_prep(const float* __restrict__ skv,
                                               float* __restrict__ wt) {
    int i = threadIdx.x + blockIdx.x * 256;
    if (i < F * K) {
        int f = i % F, k = i / F;
        wt[i] = skv[f * K + k];   // wt[k*F + f]
    }
}

__global__ __launch_bounds__(256) void sparse_conv(const float* __restrict__ in,
                                                   const float* __restrict__ wt,
                                                   const int*   __restrict__ idx,
                                                   float* __restrict__ out) {
    __shared__ float tile[5 * LROW];
    const int tx = threadIdx.x;
    const int x0 = blockIdx.x * TILE_W;
    const int h  = blockIdx.y;

    // Stage rows h-2..h+2, cols x0-2 .. x0+257 into LDS; zero outside [0,H)x[0,W).
    for (int r = 0; r < 5; ++r) {
        const int gy = h + r - HALO;
        const bool rowok = (gy >= 0 && gy < H);
        #pragma unroll
        for (int j = 0; j < 2; ++j) {
            const int c = tx + j * 256;
            if (c < LROW) {
                const int gx = x0 + c - HALO;
                float v = 0.f;
                if (rowok && gx >= 0 && gx < W) v = in[gy * W + gx];
                tile[r * LROW + c] = v;
            }
        }
    }
    __syncthreads();

    float acc[F];
    #pragma unroll
    for (int f = 0; f < F; ++f) acc[f] = 0.f;

    #pragma unroll
    for (int k = 0; k < K; ++k) {
        const int dx = idx[2 * k];       // uniform -> s_load
        const int dy = idx[2 * k + 1];
        const float v = tile[(dy + HALO) * LROW + tx + dx + HALO];  // dynamic LDS idx
        #pragma unroll
        for (int f = 0; f < F; ++f)
            acc[f] = fmaf(wt[k * F + f], v, acc[f]);  // uniform weight -> s_load
    }

    const long base = (long)h * W + (x0 + tx);
    #pragma unroll
    for (int f = 0; f < F; ++f)
        out[(long)f * (H * W) + base] = acc[f];
}

extern "C" void kernel_launch(void* const* d_in, const int* in_sizes, int n_in,
                              void* d_out, int out_size, void* d_ws, size_t ws_size,
                              hipStream_t stream) {
    const float* in  = (const float*)d_in[0];
    const float* skv = (const float*)d_in[1];
    const int*   idx = (const int*)d_in[2];
    float* out = (float*)d_out;
    float* wt  = (float*)d_ws;   // needs F*K*4 = 3200 bytes

    wt_prep<<<dim3((F * K + 255) / 256), dim3(256), 0, stream>>>(skv, wt);
    sparse_conv<<<dim3(W / TILE_W, H), dim3(256), 0, stream>>>(in, wt, idx, out);
}